// Round 1
// baseline (505.752 us; speedup 1.0000x reference)
//
#include <hip/hip_runtime.h>
#include <math.h>

// Problem constants
#define BB 8
#define TUU 128
#define THH 512
#define HDIM 512
#define VOC 32000
#define WID_ (VOC + THH)   // 32512

// ws float offsets
#define OFF_GH      0        // 8*1536
#define OFF_BIASATT 12288    // 8*512
#define OFF_CEMB    16384    // 8*512
#define OFF_LATT    20480    // 8*128   (zeroed)
#define OFF_SCORE   21504    // 8*512   (zeroed)
#define OFF_EXTRA   25600    // 8*32512 (zeroed)
#define OFF_Y       285696   // 8*1024  (context | h_new)
#define OFF_GI      293888   // 8*1536
#define OFF_PGEN    306176   // 8
#define OFF_GEN     306184   // 8*32000

#define OUT_H1 260096
#define OUT_H2 264192

__device__ __forceinline__ float wave_sum(float v) {
#pragma unroll
    for (int m = 1; m < 64; m <<= 1) v += __shfl_xor(v, m, 64);
    return v;
}

// K1: gh = gru_bhh + Whh@h ; bias_att = attn_b + W1@h ; c_embed gather
__global__ __launch_bounds__(256) void k_prep(
    const float* __restrict__ attn_W, const float* __restrict__ attn_b,
    const float* __restrict__ gru_Whh, const float* __restrict__ gru_bhh,
    const float* __restrict__ emb_W, const int* __restrict__ c_t,
    const float* __restrict__ last_h, float* __restrict__ ws)
{
    int lane = threadIdx.x & 63;
    int wid  = __builtin_amdgcn_readfirstlane(blockIdx.x * 4 + (threadIdx.x >> 6));
    if (wid < 12288) {
        int b = wid / 1536, r = wid - b * 1536;
        const float* wr = gru_Whh + (size_t)r * 512;
        const float* hv = last_h + b * 512;
        float acc = 0.f;
#pragma unroll
        for (int p = 0; p < 2; ++p) {
            int k = p * 256 + lane * 4;
            float4 w4 = *reinterpret_cast<const float4*>(wr + k);
            float4 h4 = *reinterpret_cast<const float4*>(hv + k);
            acc += w4.x * h4.x + w4.y * h4.y + w4.z * h4.z + w4.w * h4.w;
        }
        acc = wave_sum(acc);
        if (lane == 0) ws[OFF_GH + wid] = acc + gru_bhh[r];
    } else if (wid < 16384) {
        int o = wid - 12288;
        int b = o >> 9, j = o & 511;
        const float* wr = attn_W + (size_t)j * 1024;   // first half = W1
        const float* hv = last_h + b * 512;
        float acc = 0.f;
#pragma unroll
        for (int p = 0; p < 2; ++p) {
            int k = p * 256 + lane * 4;
            float4 w4 = *reinterpret_cast<const float4*>(wr + k);
            float4 h4 = *reinterpret_cast<const float4*>(hv + k);
            acc += w4.x * h4.x + w4.y * h4.y + w4.z * h4.z + w4.w * h4.w;
        }
        acc = wave_sum(acc);
        if (lane == 0) ws[OFF_BIASATT + o] = acc + attn_b[j];
    } else {
        int cw = wid - 16384;          // 0..63
        int idx = cw * 64 + lane;      // 0..4095
        int b = idx >> 9, k = idx & 511;
        ws[OFF_CEMB + idx] = emb_W[(size_t)c_t[b] * 512 + k];
    }
}

// K2/K4: C[b,t] += sum_j wvec[j] * tanh(bias[j] + sum_k A[t,b,k]*Bt[j,k])
// wave = (b, mtile of 16 t, ntile of 64 j); lanes = j; A rows via wave-uniform loads
__global__ __launch_bounds__(256) void k_enc_reduce(
    const float* __restrict__ A, const float* __restrict__ Bt,
    int bRowStride, int bColOff,
    const float* __restrict__ bias, int biasStrideB,
    const float* __restrict__ wvec, int wStrideB,
    float* __restrict__ outp, int M, int mshift)
{
    int lane = threadIdx.x & 63;
    int wid  = __builtin_amdgcn_readfirstlane(blockIdx.x * 4 + (threadIdx.x >> 6));
    int nt = wid & 7;
    int mt = (wid >> 3) & ((1 << mshift) - 1);
    int b  = wid >> (3 + mshift);
    int j  = nt * 64 + lane;
    const float* brow  = Bt + (size_t)j * bRowStride + bColOff;
    int t0 = mt * 16;
    const float* abase = A + (size_t)t0 * 4096 + b * 512;

    float acc[16];
#pragma unroll
    for (int m = 0; m < 16; ++m) acc[m] = 0.f;

    for (int k4 = 0; k4 < 128; ++k4) {
        float4 w4 = *reinterpret_cast<const float4*>(brow + k4 * 4);
#pragma unroll
        for (int m = 0; m < 16; ++m) {
            float4 a4 = *reinterpret_cast<const float4*>(abase + (size_t)m * 4096 + k4 * 4);
            acc[m] += w4.x * a4.x + w4.y * a4.y + w4.z * a4.z + w4.w * a4.w;
        }
    }
    float bb = bias[biasStrideB * b + j];
    float wv = wvec[wStrideB * b + j];
#pragma unroll
    for (int m = 0; m < 16; ++m) {
        float p = tanhf(acc[m] + bb) * wv;
        p = wave_sum(p);
        if (lane == 0) atomicAdd(outp + b * M + t0 + m, p);
    }
}

// K3a: softmax over att logits (Tu=128) + context = (sum e*enc)/S -> y[:,0:512]
__global__ __launch_bounds__(256) void k_attn_ctx(
    const float* __restrict__ u_enc, float* __restrict__ ws)
{
    __shared__ float red[256];
    __shared__ float att[128];
    int b = blockIdx.x, tid = threadIdx.x;
    float l = (tid < 128) ? ws[OFF_LATT + b * 128 + tid] : -1e30f;
    red[tid] = l; __syncthreads();
    for (int s = 128; s > 0; s >>= 1) {
        if (tid < s) red[tid] = fmaxf(red[tid], red[tid + s]);
        __syncthreads();
    }
    float mm = red[0]; __syncthreads();
    float e = (tid < 128) ? expf(l - mm) : 0.f;
    if (tid < 128) att[tid] = e;
    red[tid] = e; __syncthreads();
    for (int s = 128; s > 0; s >>= 1) {
        if (tid < s) red[tid] += red[tid + s];
        __syncthreads();
    }
    float S = red[0]; __syncthreads();
    float c0 = 0.f, c1 = 0.f;
    for (int t = 0; t < 128; ++t) {
        float a = att[t];
        const float* er = u_enc + (size_t)t * 4096 + b * 512;
        c0 += a * er[tid];
        c1 += a * er[tid + 256];
    }
    float inv = 1.0f / S;
    ws[OFF_Y + b * 1024 + tid]       = c0 * inv;
    ws[OFF_Y + b * 1024 + tid + 256] = c1 * inv;
}

// K3b: gi = gru_bih + Wih @ [c_embed, context]   (wave per output row)
__global__ __launch_bounds__(256) void k_gi(
    const float* __restrict__ gru_Wih, const float* __restrict__ gru_bih,
    float* __restrict__ ws)
{
    int lane = threadIdx.x & 63;
    int wid  = __builtin_amdgcn_readfirstlane(blockIdx.x * 4 + (threadIdx.x >> 6)); // 0..12287
    int b = wid / 1536, r = wid - b * 1536;
    const float* wr = gru_Wih + (size_t)r * 1024;
    const float* ce = ws + OFF_CEMB + b * 512;
    const float* cx = ws + OFF_Y + b * 1024;
    float acc = 0.f;
#pragma unroll
    for (int p = 0; p < 4; ++p) {
        int k = p * 256 + lane * 4;
        float4 w4 = *reinterpret_cast<const float4*>(wr + k);
        const float* xs = (p < 2) ? (ce + k) : (cx + (k - 512));
        float4 x4 = *reinterpret_cast<const float4*>(xs);
        acc += w4.x * x4.x + w4.y * x4.y + w4.z * x4.z + w4.w * x4.w;
    }
    acc = wave_sum(acc);
    if (lane == 0) ws[OFF_GI + wid] = acc + gru_bih[r];
}

// K3c: GRU elementwise -> h_new (to y[:,512:], out x2) ; pgen
__global__ __launch_bounds__(256) void k_gru(
    const float* __restrict__ last_h,
    const float* __restrict__ pgen_W, const float* __restrict__ pgen_b,
    float* __restrict__ ws, float* __restrict__ out)
{
    __shared__ float red[256];
    int b = blockIdx.x, tid = threadIdx.x;
    const float* gi = ws + OFF_GI + b * 1536;
    const float* gh = ws + OFF_GH + b * 1536;
    float pp = 0.f;
#pragma unroll
    for (int q = 0; q < 2; ++q) {
        int i = tid + q * 256;
        float r = 1.f / (1.f + expf(-(gi[i] + gh[i])));
        float z = 1.f / (1.f + expf(-(gi[512 + i] + gh[512 + i])));
        float n = tanhf(gi[1024 + i] + r * gh[1024 + i]);
        float h = last_h[b * 512 + i];
        float hn = (1.f - z) * n + z * h;
        ws[OFF_Y + b * 1024 + 512 + i] = hn;
        out[OUT_H1 + b * 512 + i] = hn;
        out[OUT_H2 + b * 512 + i] = hn;
        float cx = ws[OFF_Y + b * 1024 + i];
        float ce = ws[OFF_CEMB + b * 512 + i];
        pp += cx * pgen_W[i] + hn * pgen_W[512 + i] + ce * pgen_W[1024 + i];
    }
    red[tid] = pp; __syncthreads();
    for (int s = 128; s > 0; s >>= 1) {
        if (tid < s) red[tid] += red[tid + s];
        __syncthreads();
    }
    if (tid == 0) ws[OFF_PGEN + b] = 1.f / (1.f + expf(-(red[0] + pgen_b[0])));
}

// K5: gen_score[b,v] = y[b,:] . proj_W[v,:] + proj_b[v]
// lane = (b, kgroup of 4); wave = 8 rows; proj_W streamed once, y in LDS
__global__ __launch_bounds__(256) void k_proj(
    const float* __restrict__ projW, const float* __restrict__ projb,
    float* __restrict__ ws)
{
    __shared__ float ys[8 * 1032];
    int tid = threadIdx.x;
#pragma unroll
    for (int q = 0; q < 8; ++q) {
        int idx = (q * 256 + tid) * 4;       // float index into y (8192)
        int b = idx >> 10, k = idx & 1023;
        float4 v = *reinterpret_cast<const float4*>(ws + OFF_Y + idx);
        *reinterpret_cast<float4*>(&ys[b * 1032 + k]) = v;
    }
    __syncthreads();
    int lane = tid & 63;
    int w    = __builtin_amdgcn_readfirstlane(tid >> 6);
    int vbase = (blockIdx.x * 4 + w) * 8;
    int bq = lane >> 3, kg = lane & 7;
    float acc[8];
#pragma unroll
    for (int r = 0; r < 8; ++r) acc[r] = 0.f;
    const float* wbase = projW + (size_t)vbase * 1024 + kg * 4;
    for (int c = 0; c < 32; ++c) {
        float4 y4 = *reinterpret_cast<const float4*>(&ys[bq * 1032 + c * 32 + kg * 4]);
#pragma unroll
        for (int r = 0; r < 8; ++r) {
            float4 w4 = *reinterpret_cast<const float4*>(wbase + (size_t)r * 1024 + c * 32);
            acc[r] += w4.x * y4.x + w4.y * y4.y + w4.z * y4.z + w4.w * y4.w;
        }
    }
#pragma unroll
    for (int r = 0; r < 8; ++r) {
        acc[r] += __shfl_xor(acc[r], 1, 64);
        acc[r] += __shfl_xor(acc[r], 2, 64);
        acc[r] += __shfl_xor(acc[r], 4, 64);
    }
    if (kg == 0) {
#pragma unroll
        for (int r = 0; r < 8; ++r)
            ws[OFF_GEN + bq * 32000 + vbase + r] = acc[r] + projb[vbase + r];
    }
}

// K6: copy-softmax (sparse analytic), global softmax over 64512, write proba
__global__ __launch_bounds__(1024) void k_final(
    const int* __restrict__ htok, float* __restrict__ ws, float* __restrict__ out)
{
    __shared__ float red[1024];
    __shared__ float es[512];
    int b = blockIdx.x, tid = threadIdx.x;
    float s = (tid < 512) ? ws[OFF_SCORE + b * 512 + tid] : -1e30f;
    red[tid] = s; __syncthreads();
    for (int t = 512; t > 0; t >>= 1) {
        if (tid < t) red[tid] = fmaxf(red[tid], red[tid + t]);
        __syncthreads();
    }
    float m = red[0]; __syncthreads();
    float e = (tid < 512) ? expf(s - m) : 0.f;
    if (tid < 512) es[tid] = e;
    red[tid] = e; __syncthreads();
    for (int t = 512; t > 0; t >>= 1) {
        if (tid < t) red[tid] += red[tid + t];
        __syncthreads();
    }
    float S = red[0]; __syncthreads();

    float* extra = ws + OFF_EXTRA + b * WID_;
    if (tid < 511) {
        int tok = htok[tid * 8 + b];
        int col = (tok == 2) ? (VOC + tid) : tok;
        float val = (tok == 2) ? 5.0f : 1.0f;
        atomicAdd(extra + col, (val - 1e-10f) * es[tid + 1]);
    }
    __syncthreads();

    const float* gen = ws + OFF_GEN + b * VOC;
    float gp = ws[OFF_PGEN + b];
    float cq = 1.f - gp;
    float epsS = 1e-10f * S;
    float lm = -1e30f;
    for (int v = tid; v < VOC; v += 1024) lm = fmaxf(lm, gp * gen[v]);
    for (int w = tid; w < WID_; w += 1024) {
        float cv = cq * (logf(epsS + extra[w]) + m);
        extra[w] = cv;
        lm = fmaxf(lm, cv);
    }
    red[tid] = lm; __syncthreads();
    for (int t = 512; t > 0; t >>= 1) {
        if (tid < t) red[tid] = fmaxf(red[tid], red[tid + t]);
        __syncthreads();
    }
    float M = red[0]; __syncthreads();
    float ld = 0.f;
    for (int v = tid; v < VOC; v += 1024) ld += expf(gp * gen[v] - M);
    for (int w = tid; w < WID_; w += 1024) ld += expf(extra[w] - M);
    red[tid] = ld; __syncthreads();
    for (int t = 512; t > 0; t >>= 1) {
        if (tid < t) red[tid] += red[tid + t];
        __syncthreads();
    }
    float inv = 1.f / red[0];
    float* ob = out + b * WID_;
    for (int v = tid; v < VOC; v += 1024)
        ob[v] = (expf(gp * gen[v] - M) + expf(extra[v] - M)) * inv;
    for (int w = VOC + tid; w < WID_; w += 1024)
        ob[w] = expf(extra[w] - M) * inv;
}

extern "C" void kernel_launch(void* const* d_in, const int* in_sizes, int n_in,
                              void* d_out, int out_size, void* d_ws, size_t ws_size,
                              hipStream_t stream)
{
    (void)in_sizes; (void)n_in; (void)out_size; (void)ws_size;
    const int*   htok  = (const int*)d_in[0];
    const float* henc  = (const float*)d_in[1];
    const float* uenc  = (const float*)d_in[2];
    const int*   ct    = (const int*)d_in[3];
    const float* lasth = (const float*)d_in[4];
    const float* embW  = (const float*)d_in[5];
    const float* attnW = (const float*)d_in[6];
    const float* attnb = (const float*)d_in[7];
    const float* attnv = (const float*)d_in[8];
    const float* gWih  = (const float*)d_in[9];
    const float* gWhh  = (const float*)d_in[10];
    const float* gbih  = (const float*)d_in[11];
    const float* gbhh  = (const float*)d_in[12];
    const float* projW = (const float*)d_in[13];
    const float* projb = (const float*)d_in[14];
    const float* c2W   = (const float*)d_in[15];
    const float* c2b   = (const float*)d_in[16];
    const float* pgW   = (const float*)d_in[17];
    const float* pgb   = (const float*)d_in[18];
    float* ws  = (float*)d_ws;
    float* out = (float*)d_out;

    // zero atomic-accumulation regions: LATT, SCORE, EXTRA (contiguous)
    hipMemsetAsync((char*)d_ws + (size_t)OFF_LATT * 4, 0,
                   (size_t)(OFF_Y - OFF_LATT) * 4, stream);

    k_prep<<<4112, 256, 0, stream>>>(attnW, attnb, gWhh, gbhh, embW, ct, lasth, ws);
    // attention energy: A=u_enc (M=128), Bt=attn_W[:,512:], bias=bias_att[b,j], wvec=attn_v
    k_enc_reduce<<<128, 256, 0, stream>>>(uenc, attnW, 1024, 512,
                                          ws + OFF_BIASATT, 512, attnv, 0,
                                          ws + OFF_LATT, 128, 3);
    k_attn_ctx<<<8, 256, 0, stream>>>(uenc, ws);
    k_gi<<<3072, 256, 0, stream>>>(gWih, gbih, ws);
    k_gru<<<8, 256, 0, stream>>>(lasth, pgW, pgb, ws, out);
    // copy score: A=history_enc (M=512), Bt=copy2_W, bias=copy2_b, wvec=h_new[b,j]
    k_enc_reduce<<<512, 256, 0, stream>>>(henc, c2W, 512, 0,
                                          c2b, 0, ws + OFF_Y + 512, 1024,
                                          ws + OFF_SCORE, 512, 5);
    k_proj<<<1000, 256, 0, stream>>>(projW, projb, ws);
    k_final<<<8, 1024, 0, stream>>>(htok, ws, out);
}

// Round 2
// 359.161 us; speedup vs baseline: 1.4081x; 1.4081x over previous
//
#include <hip/hip_runtime.h>
#include <math.h>

// Problem constants
#define BB 8
#define TUU 128
#define THH 512
#define HDIM 512
#define VOC 32000
#define WID_ (VOC + THH)   // 32512

// ws float offsets
#define OFF_GH      0        // 8*1536
#define OFF_BIASATT 12288    // 8*512
#define OFF_CEMB    16384    // 8*512
#define OFF_LATT    20480    // 8*128   (zeroed)
#define OFF_SSUM    21504    // 8       (zeroed)
#define OFF_SCORE   21568    // 8*512   (zeroed)
#define OFF_EXTRA   25664    // 8*32512 (zeroed)
#define OFF_Y       285760   // 8*1024  (context | h_new)
#define OFF_GI      293952   // 8*1536
#define OFF_PGEN    306240   // 8
#define OFF_M       306248   // 8
#define OFF_EPS     306256   // 8
#define OFF_WSPLIT_BYTES 1225056   // = (306256+8)*4 ; u16 arrays start here
// u16 offsets from OFF_WSPLIT_BYTES: WC_HI 0, WC_LO 262144, WA_HI 524288, WA_LO 786432

#define OUT_H1 260096
#define OUT_H2 264192

#define SM_SHIFT 20.0f

typedef __attribute__((ext_vector_type(8))) short short8;
typedef __attribute__((ext_vector_type(4))) float f32x4;

__device__ __forceinline__ float wave_sum(float v) {
#pragma unroll
    for (int m = 1; m < 64; m <<= 1) v += __shfl_xor(v, m, 64);
    return v;
}

__device__ __forceinline__ unsigned short f2bf(float x) {
    unsigned int u = __float_as_uint(x);
    unsigned int r = (u + 0x7fffu + ((u >> 16) & 1u)) >> 16;
    return (unsigned short)r;
}
__device__ __forceinline__ float bf2f(unsigned short h) {
    return __uint_as_float(((unsigned int)h) << 16);
}

// K0: split-convert c2W and attn_W2 (cols 512..1024) to bf16 hi/lo arrays in ws
__global__ __launch_bounds__(256) void k_cvt(
    const float* __restrict__ c2W, const float* __restrict__ attnW,
    unsigned short* __restrict__ wbase)
{
    int i = blockIdx.x * 256 + threadIdx.x;   // 0..262143
    float x = c2W[i];
    unsigned short h = f2bf(x);
    wbase[i] = h;
    wbase[262144 + i] = f2bf(x - bf2f(h));
    int j = i >> 9, k = i & 511;
    float y = attnW[(size_t)j * 1024 + 512 + k];
    unsigned short h2 = f2bf(y);
    wbase[524288 + i] = h2;
    wbase[786432 + i] = f2bf(y - bf2f(h2));
}

// K1: gh = gru_bhh + Whh@h (all 8 b per wave); bias_att = attn_b + W1@h; c_embed
__global__ __launch_bounds__(256) void k_prep(
    const float* __restrict__ attn_W, const float* __restrict__ attn_b,
    const float* __restrict__ gru_Whh, const float* __restrict__ gru_bhh,
    const float* __restrict__ emb_W, const int* __restrict__ c_t,
    const float* __restrict__ last_h, float* __restrict__ ws)
{
    int lane = threadIdx.x & 63;
    int wid  = __builtin_amdgcn_readfirstlane(blockIdx.x * 4 + (threadIdx.x >> 6));
    if (wid < 2048) {
        const float* wr;
        if (wid < 1536) wr = gru_Whh + (size_t)wid * 512;
        else            wr = attn_W + (size_t)(wid - 1536) * 1024;
        int k = lane * 8;
        float4 w0 = *reinterpret_cast<const float4*>(wr + k);
        float4 w1 = *reinterpret_cast<const float4*>(wr + k + 4);
        float acc[8];
#pragma unroll
        for (int b = 0; b < 8; ++b) {
            const float* hv = last_h + b * 512 + k;
            float4 h0 = *reinterpret_cast<const float4*>(hv);
            float4 h1 = *reinterpret_cast<const float4*>(hv + 4);
            acc[b] = w0.x*h0.x + w0.y*h0.y + w0.z*h0.z + w0.w*h0.w
                   + w1.x*h1.x + w1.y*h1.y + w1.z*h1.z + w1.w*h1.w;
        }
#pragma unroll
        for (int b = 0; b < 8; ++b) acc[b] = wave_sum(acc[b]);
        if (lane == 0) {
            if (wid < 1536) {
                float bias = gru_bhh[wid];
#pragma unroll
                for (int b = 0; b < 8; ++b) ws[OFF_GH + b * 1536 + wid] = acc[b] + bias;
            } else {
                int j = wid - 1536;
                float bias = attn_b[j];
#pragma unroll
                for (int b = 0; b < 8; ++b) ws[OFF_BIASATT + b * 512 + j] = acc[b] + bias;
            }
        }
    } else {
        int cw = wid - 2048;           // 0..63
        int idx = cw * 64 + lane;      // 0..4095
        int b = idx >> 9, k = idx & 511;
        ws[OFF_CEMB + idx] = emb_W[(size_t)c_t[b] * 512 + k];
    }
}

// K2: fused tanh-GEMM via split-bf16 MFMA.
// out[b, t] += sum_j tanh( (A@W^T)[r,j] + bias[b,j] ) * wv[b,j],  r = t*8+b
// A: [R,512] fp32 rows; Whi/Wlo: [512][512] bf16 split; block = 64 rows x 128 j
__global__ __launch_bounds__(256) void k_mfma_tanh(
    const float* __restrict__ A,
    const unsigned short* __restrict__ Whi, const unsigned short* __restrict__ Wlo,
    const float* __restrict__ bias, int bstride,
    const float* __restrict__ wvp, int wstride,
    float* __restrict__ outp, int Mout)
{
    __shared__ short As[2][64][40];
    __shared__ short Ws[2][128][40];
    int tid  = threadIdx.x;
    int lane = tid & 63;
    int wv   = tid >> 6;           // wave 0..3
    int rbase = blockIdx.x * 64;
    int j0    = blockIdx.y * 128;

    f32x4 acc[4][2];
#pragma unroll
    for (int mt = 0; mt < 4; ++mt)
#pragma unroll
        for (int nt = 0; nt < 2; ++nt) acc[mt][nt] = (f32x4)0.0f;

    int q8  = (lane >> 4) * 8;
    int l15 = lane & 15;
    int ra  = tid >> 2, kk = (tid & 3) * 8;       // A staging coords
    int jw  = tid >> 1, kh = (tid & 1) * 16;      // W staging coords

    for (int kc = 0; kc < 16; ++kc) {
        int k0 = kc * 32;
        // stage A (64x32 fp32 -> split bf16)
        {
            const float* ap = A + (size_t)(rbase + ra) * 512 + k0 + kk;
            float4 a0 = *reinterpret_cast<const float4*>(ap);
            float4 a1 = *reinterpret_cast<const float4*>(ap + 4);
            float vals[8] = {a0.x, a0.y, a0.z, a0.w, a1.x, a1.y, a1.z, a1.w};
            union { short8 v; short s[8]; } hi, lo;
#pragma unroll
            for (int i = 0; i < 8; ++i) {
                unsigned short h = f2bf(vals[i]);
                hi.s[i] = (short)h;
                lo.s[i] = (short)f2bf(vals[i] - bf2f(h));
            }
            *reinterpret_cast<short8*>(&As[0][ra][kk]) = hi.v;
            *reinterpret_cast<short8*>(&As[1][ra][kk]) = lo.v;
        }
        // stage W (128x32 u16 hi+lo, pure copy)
        {
            const short8* wph = reinterpret_cast<const short8*>(Whi + (size_t)(j0 + jw) * 512 + k0 + kh);
            const short8* wpl = reinterpret_cast<const short8*>(Wlo + (size_t)(j0 + jw) * 512 + k0 + kh);
            *reinterpret_cast<short8*>(&Ws[0][jw][kh])     = wph[0];
            *reinterpret_cast<short8*>(&Ws[0][jw][kh + 8]) = wph[1];
            *reinterpret_cast<short8*>(&Ws[1][jw][kh])     = wpl[0];
            *reinterpret_cast<short8*>(&Ws[1][jw][kh + 8]) = wpl[1];
        }
        __syncthreads();

        short8 ah[4], al[4], bh[2], bl[2];
#pragma unroll
        for (int mt = 0; mt < 4; ++mt) {
            ah[mt] = *reinterpret_cast<const short8*>(&As[0][mt * 16 + l15][q8]);
            al[mt] = *reinterpret_cast<const short8*>(&As[1][mt * 16 + l15][q8]);
        }
#pragma unroll
        for (int nt = 0; nt < 2; ++nt) {
            bh[nt] = *reinterpret_cast<const short8*>(&Ws[0][wv * 32 + nt * 16 + l15][q8]);
            bl[nt] = *reinterpret_cast<const short8*>(&Ws[1][wv * 32 + nt * 16 + l15][q8]);
        }
#pragma unroll
        for (int mt = 0; mt < 4; ++mt)
#pragma unroll
            for (int nt = 0; nt < 2; ++nt) {
                acc[mt][nt] = __builtin_amdgcn_mfma_f32_16x16x32_bf16(ah[mt], bh[nt], acc[mt][nt], 0, 0, 0);
                acc[mt][nt] = __builtin_amdgcn_mfma_f32_16x16x32_bf16(ah[mt], bl[nt], acc[mt][nt], 0, 0, 0);
                acc[mt][nt] = __builtin_amdgcn_mfma_f32_16x16x32_bf16(al[mt], bh[nt], acc[mt][nt], 0, 0, 0);
            }
        __syncthreads();
    }

    // epilogue: tanh, weight, reduce over j (128 cols of this block), atomicAdd
    int q = lane >> 4;
#pragma unroll
    for (int mt = 0; mt < 4; ++mt) {
        float s[4];
#pragma unroll
        for (int r = 0; r < 4; ++r) {
            int row = rbase + mt * 16 + q * 4 + r;
            int b = row & 7;
            float v = 0.f;
#pragma unroll
            for (int nt = 0; nt < 2; ++nt) {
                int jj = j0 + wv * 32 + nt * 16 + l15;
                float e = acc[mt][nt][r] + bias[b * bstride + jj];
                v += tanhf(e) * wvp[b * wstride + jj];
            }
#pragma unroll
            for (int m = 1; m < 16; m <<= 1) v += __shfl_xor(v, m, 64);
            s[r] = v;
        }
        if (l15 == 0) {
#pragma unroll
            for (int r = 0; r < 4; ++r) {
                int row = rbase + mt * 16 + q * 4 + r;
                atomicAdd(outp + (row & 7) * Mout + (row >> 3), s[r]);
            }
        }
    }
}

// K3a: softmax over att logits (Tu=128) + context -> y[:,0:512]
__global__ __launch_bounds__(256) void k_attn_ctx(
    const float* __restrict__ u_enc, float* __restrict__ ws)
{
    __shared__ float red[256];
    __shared__ float att[128];
    int b = blockIdx.x, tid = threadIdx.x;
    float l = (tid < 128) ? ws[OFF_LATT + b * 128 + tid] : -1e30f;
    red[tid] = l; __syncthreads();
    for (int s = 128; s > 0; s >>= 1) {
        if (tid < s) red[tid] = fmaxf(red[tid], red[tid + s]);
        __syncthreads();
    }
    float mm = red[0]; __syncthreads();
    float e = (tid < 128) ? expf(l - mm) : 0.f;
    if (tid < 128) att[tid] = e;
    red[tid] = e; __syncthreads();
    for (int s = 128; s > 0; s >>= 1) {
        if (tid < s) red[tid] += red[tid + s];
        __syncthreads();
    }
    float S = red[0]; __syncthreads();
    float c0 = 0.f, c1 = 0.f;
    for (int t = 0; t < 128; ++t) {
        float a = att[t];
        const float* er = u_enc + (size_t)t * 4096 + b * 512;
        c0 += a * er[tid];
        c1 += a * er[tid + 256];
    }
    float inv = 1.0f / S;
    ws[OFF_Y + b * 1024 + tid]       = c0 * inv;
    ws[OFF_Y + b * 1024 + tid + 256] = c1 * inv;
}

// K3b: gi = gru_bih + Wih @ [c_embed, context]  (wave per row, all 8 b)
__global__ __launch_bounds__(256) void k_gi(
    const float* __restrict__ gru_Wih, const float* __restrict__ gru_bih,
    float* __restrict__ ws)
{
    int lane = threadIdx.x & 63;
    int r = __builtin_amdgcn_readfirstlane(blockIdx.x * 4 + (threadIdx.x >> 6)); // 0..1535
    const float* wr = gru_Wih + (size_t)r * 1024;
    float4 w[4];
#pragma unroll
    for (int p = 0; p < 4; ++p)
        w[p] = *reinterpret_cast<const float4*>(wr + lane * 4 + p * 256);
    float acc[8];
#pragma unroll
    for (int b = 0; b < 8; ++b) {
        acc[b] = 0.f;
#pragma unroll
        for (int p = 0; p < 4; ++p) {
            int k = lane * 4 + p * 256;
            const float* xs = (p < 2) ? (ws + OFF_CEMB + b * 512 + k)
                                      : (ws + OFF_Y + b * 1024 + (k - 512));
            float4 x4 = *reinterpret_cast<const float4*>(xs);
            acc[b] += w[p].x*x4.x + w[p].y*x4.y + w[p].z*x4.z + w[p].w*x4.w;
        }
    }
#pragma unroll
    for (int b = 0; b < 8; ++b) acc[b] = wave_sum(acc[b]);
    if (lane == 0) {
        float bias = gru_bih[r];
#pragma unroll
        for (int b = 0; b < 8; ++b) ws[OFF_GI + b * 1536 + r] = acc[b] + bias;
    }
}

// K3c: GRU elementwise -> h_new ; pgen
__global__ __launch_bounds__(256) void k_gru(
    const float* __restrict__ last_h,
    const float* __restrict__ pgen_W, const float* __restrict__ pgen_b,
    float* __restrict__ ws, float* __restrict__ out)
{
    __shared__ float red[256];
    int b = blockIdx.x, tid = threadIdx.x;
    const float* gi = ws + OFF_GI + b * 1536;
    const float* gh = ws + OFF_GH + b * 1536;
    float pp = 0.f;
#pragma unroll
    for (int q = 0; q < 2; ++q) {
        int i = tid + q * 256;
        float r = 1.f / (1.f + expf(-(gi[i] + gh[i])));
        float z = 1.f / (1.f + expf(-(gi[512 + i] + gh[512 + i])));
        float n = tanhf(gi[1024 + i] + r * gh[1024 + i]);
        float h = last_h[b * 512 + i];
        float hn = (1.f - z) * n + z * h;
        ws[OFF_Y + b * 1024 + 512 + i] = hn;
        out[OUT_H1 + b * 512 + i] = hn;
        out[OUT_H2 + b * 512 + i] = hn;
        float cx = ws[OFF_Y + b * 1024 + i];
        float ce = ws[OFF_CEMB + b * 512 + i];
        pp += cx * pgen_W[i] + hn * pgen_W[512 + i] + ce * pgen_W[1024 + i];
    }
    red[tid] = pp; __syncthreads();
    for (int s = 128; s > 0; s >>= 1) {
        if (tid < s) red[tid] += red[tid + s];
        __syncthreads();
    }
    if (tid == 0) ws[OFF_PGEN + b] = 1.f / (1.f + expf(-(red[0] + pgen_b[0])));
}

// K5: gen_score -> out[b*32512 + v]; y held in VGPRs, proj_W streamed coalesced
__global__ __launch_bounds__(256) void k_proj(
    const float* __restrict__ projW, const float* __restrict__ projb,
    const float* __restrict__ ws, float* __restrict__ out)
{
    int lane = threadIdx.x & 63;
    int gw = blockIdx.x * 4 + (threadIdx.x >> 6);
    int nw = gridDim.x * 4;
    float4 yreg[8][4];
#pragma unroll
    for (int b = 0; b < 8; ++b)
#pragma unroll
        for (int p = 0; p < 4; ++p)
            yreg[b][p] = *reinterpret_cast<const float4*>(ws + OFF_Y + b * 1024 + p * 256 + lane * 4);

    for (int v = gw; v < VOC; v += nw) {
        const float4* wr = reinterpret_cast<const float4*>(projW + (size_t)v * 1024);
        float4 w0 = wr[lane], w1 = wr[64 + lane], w2 = wr[128 + lane], w3 = wr[192 + lane];
        float acc[8];
#pragma unroll
        for (int b = 0; b < 8; ++b) {
            acc[b] = w0.x*yreg[b][0].x + w0.y*yreg[b][0].y + w0.z*yreg[b][0].z + w0.w*yreg[b][0].w
                   + w1.x*yreg[b][1].x + w1.y*yreg[b][1].y + w1.z*yreg[b][1].z + w1.w*yreg[b][1].w
                   + w2.x*yreg[b][2].x + w2.y*yreg[b][2].y + w2.z*yreg[b][2].z + w2.w*yreg[b][2].w
                   + w3.x*yreg[b][3].x + w3.y*yreg[b][3].y + w3.z*yreg[b][3].z + w3.w*yreg[b][3].w;
        }
#pragma unroll
        for (int b = 0; b < 8; ++b) acc[b] = wave_sum(acc[b]);
        if (lane == 0) {
            float pb = projb[v];
#pragma unroll
            for (int b = 0; b < 8; ++b) out[b * WID_ + v] = acc[b] + pb;
        }
    }
}

// K6a: per-batch softmax over copy scores + sparse scatter of es into extra
__global__ __launch_bounds__(512) void k_copy_sm(
    const int* __restrict__ htok, float* __restrict__ ws)
{
    __shared__ float red[512];
    __shared__ float es[512];
    int b = blockIdx.x, t = threadIdx.x;
    float s = ws[OFF_SCORE + b * 512 + t];
    red[t] = s; __syncthreads();
    for (int st = 256; st > 0; st >>= 1) {
        if (t < st) red[t] = fmaxf(red[t], red[t + st]);
        __syncthreads();
    }
    float m = red[0]; __syncthreads();
    float e = expf(s - m);
    es[t] = e; red[t] = e; __syncthreads();
    for (int st = 256; st > 0; st >>= 1) {
        if (t < st) red[t] += red[t + st];
        __syncthreads();
    }
    if (t == 0) {
        ws[OFF_M + b]   = m;
        ws[OFF_EPS + b] = 1e-10f * red[0];
    }
    if (t < 511) {
        int tok = htok[t * 8 + b];
        int col = (tok == 2) ? (VOC + t) : tok;
        float val = (tok == 2) ? 5.0f : 1.0f;
        atomicAdd(ws + OFF_EXTRA + b * WID_ + col, (val - 1e-10f) * es[t + 1]);
    }
}

// K6b: numerators (shifted-exp, no max pass) + per-block partial sums
__global__ __launch_bounds__(256) void k_numer(
    float* __restrict__ ws, float* __restrict__ out)
{
    __shared__ float red[256];
    int b = blockIdx.x, tid = threadIdx.x;
    int start = blockIdx.y * 2032;
    float gp   = ws[OFF_PGEN + b];
    float cq   = 1.f - gp;
    float m    = ws[OFF_M + b];
    float epsS = ws[OFF_EPS + b];
    float loc = 0.f;
    for (int w = start + tid; w < start + 2032; w += 256) {
        float ex = ws[OFF_EXTRA + b * WID_ + w];
        float cv = cq * (logf(epsS + ex) + m);
        float num = expf(cv - SM_SHIFT);
        if (w < VOC) num += expf(gp * out[b * WID_ + w] - SM_SHIFT);
        out[b * WID_ + w] = num;
        loc += num;
    }
    red[tid] = loc; __syncthreads();
    for (int st = 128; st > 0; st >>= 1) {
        if (tid < st) red[tid] += red[tid + st];
        __syncthreads();
    }
    if (tid == 0) atomicAdd(ws + OFF_SSUM + b, red[0]);
}

// K6c: scale by 1/sum
__global__ __launch_bounds__(256) void k_scale(
    const float* __restrict__ ws, float* __restrict__ out)
{
    int b = blockIdx.x, tid = threadIdx.x;
    int start = blockIdx.y * 2032;
    float inv = 1.f / ws[OFF_SSUM + b];
    for (int w = start + tid; w < start + 2032; w += 256)
        out[b * WID_ + w] *= inv;
}

extern "C" void kernel_launch(void* const* d_in, const int* in_sizes, int n_in,
                              void* d_out, int out_size, void* d_ws, size_t ws_size,
                              hipStream_t stream)
{
    (void)in_sizes; (void)n_in; (void)out_size; (void)ws_size;
    const int*   htok  = (const int*)d_in[0];
    const float* henc  = (const float*)d_in[1];
    const float* uenc  = (const float*)d_in[2];
    const int*   ct    = (const int*)d_in[3];
    const float* lasth = (const float*)d_in[4];
    const float* embW  = (const float*)d_in[5];
    const float* attnW = (const float*)d_in[6];
    const float* attnb = (const float*)d_in[7];
    const float* attnv = (const float*)d_in[8];
    const float* gWih  = (const float*)d_in[9];
    const float* gWhh  = (const float*)d_in[10];
    const float* gbih  = (const float*)d_in[11];
    const float* gbhh  = (const float*)d_in[12];
    const float* projW = (const float*)d_in[13];
    const float* projb = (const float*)d_in[14];
    const float* c2W   = (const float*)d_in[15];
    const float* c2b   = (const float*)d_in[16];
    const float* pgW   = (const float*)d_in[17];
    const float* pgb   = (const float*)d_in[18];
    float* ws  = (float*)d_ws;
    float* out = (float*)d_out;
    unsigned short* wsplit = (unsigned short*)((char*)d_ws + OFF_WSPLIT_BYTES);

    // zero atomic-accumulation regions: LATT, SSUM, SCORE, EXTRA (contiguous)
    hipMemsetAsync((char*)d_ws + (size_t)OFF_LATT * 4, 0,
                   (size_t)(OFF_Y - OFF_LATT) * 4, stream);

    k_cvt<<<1024, 256, 0, stream>>>(c2W, attnW, wsplit);
    k_prep<<<528, 256, 0, stream>>>(attnW, attnb, gWhh, gbhh, embW, ct, lasth, ws);
    // attention energy GEMM: A=u_enc [1024,512], W=attn_W2 split, out=latt [b][128]
    k_mfma_tanh<<<dim3(16, 4), 256, 0, stream>>>(
        uenc, wsplit + 524288, wsplit + 786432,
        ws + OFF_BIASATT, 512, attnv, 0, ws + OFF_LATT, 128);
    k_attn_ctx<<<8, 256, 0, stream>>>(uenc, ws);
    k_gi<<<384, 256, 0, stream>>>(gWih, gbih, ws);
    k_gru<<<8, 256, 0, stream>>>(lasth, pgW, pgb, ws, out);
    // copy score GEMM: A=hist [4096,512], W=c2W split, wv=h_new, out=score [b][512]
    k_mfma_tanh<<<dim3(64, 4), 256, 0, stream>>>(
        henc, wsplit, wsplit + 262144,
        c2b, 0, ws + OFF_Y + 512, 1024, ws + OFF_SCORE, 512);
    k_proj<<<500, 256, 0, stream>>>(projW, projb, ws, out);
    k_copy_sm<<<8, 512, 0, stream>>>(htok, ws);
    k_numer<<<dim3(8, 16), 256, 0, stream>>>(ws, out);
    k_scale<<<dim3(8, 16), 256, 0, stream>>>(ws, out);
}